// Round 4
// baseline (226.751 us; speedup 1.0000x reference)
//
#include <hip/hip_runtime.h>

// Problem constants (fixed by setup_inputs):
//   x: [B=64, D=64, H=32, W=32] fp32   -> N = B*H*W = 65536 rows of D=64
//   codebook: [K=512, D=64] fp32
// Output layout (all fp32, concatenated flat in return order):
//   [0 .. 4194304)        quant_out [B,D,H,W]
//   [4194304]             loss
//   [4194305]             perplexity
//   [4194306 .. +65536)   encoding_indice [B, H*W] (as float)
//   [4259842 .. +32768)   index_program [B,K]
//   [4292610 .. +32768)   softmax_histogram [B,K]

#define OFF_LOSS 4194304
#define OFF_PERP 4194305
#define OFF_ENC  4194306
#define OFF_IP   4259842
#define OFF_SH   4292610

// Workspace layout (floats). Requires ws_size >= 1090048*4 B = 4.4 MB.
//   cbT  [4][64][128]        chunk-major transposed codebook
//   ce2  [512]               ||e_k||^2
//   sh partials [2048][512]  per-block softmax-histogram partial
//   loss partials [2048*4]   per-wave loss partial
#define WS_CBT   0
#define WS_CE2   32768
#define WS_SHP   33280
#define WS_LOSS  1081856

// R11 change (one token; math bit-identical to R10):
//  - __launch_bounds__(256,3) -> (256,1). Empirical allocator law on this
//    toolchain: VGPR cap = 256/min_waves (R8: (256,3)->84, R9: (256,2)->128,
//    R10: (256,3)->80 -- NOT 512/min_waves). Every prior round spilled the
//    ~130-reg working set (acc[4][16]=64 + pv[8]=32 + temps); R10's cap of
//    80 spilled ~50 regs -> ~207 MB excess scratch WRITE and 29% VALUBusy.
//    (256,1) -> cap 256: zero spill. Runtime occupancy is set by ACTUAL
//    usage: LDS 42.5 KB -> 3 blocks/CU; ~135 VGPRs -> 3 waves/SIMD. Same
//    12 waves/CU as R10 targeted, minus the scratch round-trips.

__global__ __launch_bounds__(256) void vq_prep(const float* __restrict__ cb,
                                               float* __restrict__ ws)
{
    const int t  = blockIdx.x * 256 + threadIdx.x;   // 0..8191
    const int kg = t >> 4;                           // code 0..511
    const int j  = t & 15;                           // float4 index along D
    const float4 v = ((const float4*)cb)[(kg << 4) + j];
    float pr = v.x * v.x + v.y * v.y + v.z * v.z + v.w * v.w;
    #pragma unroll
    for (int off = 1; off < 16; off <<= 1) pr += __shfl_xor(pr, off, 16);
    if (j == 0) ws[WS_CE2 + kg] = pr;
    // transposed, chunk-major: ws[WS_CBT + kc*8192 + d*128 + kl]
    const int kc = kg >> 7, kl = kg & 127;
    float* base = ws + WS_CBT + (kc << 13) + (j << 9) + kl;   // d = 4*j
    base[0]   = v.x;
    base[128] = v.y;
    base[256] = v.z;
    base[384] = v.w;
}

__global__ __launch_bounds__(256, 1) void vq_main(
    const float* __restrict__ x, const float* __restrict__ cb,
    const float* __restrict__ wsc,   // cbT + ce2 (read-only region)
    float* __restrict__ wso,         // sh + loss partials (write-only region)
    float* __restrict__ out)
{
    __shared__ float  xs[64 * 32];     // xs[d*32 + r], transposed x tile (32 rows)
    __shared__ float  csT[64 * 128];   // [d][k] for current 128-code chunk
    __shared__ float  ce2[512];        // ||e_k||^2 (fp32)
    __shared__ float  sxx[32];         // ||x_r||^2 (fp32) per row
    __shared__ int    sidx[32];        // argmin code per row

    const int t    = threadIdx.x;
    const int blk  = blockIdx.x;        // 0..2047
    const int b    = blk >> 5;          // batch index
    const int row0 = (blk & 31) << 5;   // row offset within batch (H*W space)
    const int tr   = t >> 5;            // 0..7  (row group: rows tr*4..tr*4+3)
    const int tc   = t & 31;            // 0..31 (col group)

    const float4* cbT4 = (const float4*)(wsc + WS_CBT);

    // ---- stage x tile as float4 (512 float4, 2 per thread, coalesced) ----
    {
        const float4* xb4 = (const float4*)(x + ((size_t)b << 16) + row0);
        #pragma unroll
        for (int p = 0; p < 2; ++p) {
            const int fi = (p << 8) + t;      // 0..511
            const int d  = fi >> 3;
            const int r4 = fi & 7;
            *(float4*)&xs[(d << 5) + (r4 << 2)] = xb4[(d << 8) + r4];
        }
    }
    // ---- stage ce2 from ws ----
    if (t < 128) ((float4*)ce2)[t] = ((const float4*)(wsc + WS_CE2))[t];

    // ---- prefetch chunk 0 of transposed codebook into registers ----
    float4 pv[8];
    #pragma unroll
    for (int p = 0; p < 8; ++p) pv[p] = cbT4[(p << 8) + t];

    __syncthreads();
    // ---- ||x_r||^2 fp32, sequential fmaf over d (bit-exact) ----
    if (t < 32) {
        float s = 0.f;
        for (int d = 0; d < 64; ++d) { const float v = xs[(d << 5) + t]; s = fmaf(v, v, s); }
        sxx[t] = s;
    }

    float acc[4][16];
    #pragma unroll
    for (int i = 0; i < 4; ++i)
        #pragma unroll
        for (int c = 0; c < 16; ++c) acc[i][c] = 0.f;

    // ---- GEMM: 4 chunks of 128 codes ----
    #pragma unroll
    for (int kc = 0; kc < 4; ++kc) {
        __syncthreads();   // csT free (prior chunk's reads done); sxx visible
        // stage csT linearly from registers (pre-transposed in ws)
        #pragma unroll
        for (int p = 0; p < 8; ++p) ((float4*)csT)[(p << 8) + t] = pv[p];
        // issue next chunk's global loads now; they complete during the d-loop
        if (kc < 3) {
            #pragma unroll
            for (int p = 0; p < 8; ++p) pv[p] = cbT4[((kc + 1) << 11) + (p << 8) + t];
        }
        __syncthreads();   // csT ready
        #pragma unroll 2
        for (int db = 0; db < 16; ++db) {
            const float* cbase = &csT[(db << 9) + (tc << 2)];
            #pragma unroll
            for (int j = 0; j < 4; ++j) {
                const int d = (db << 2) + j;
                const float4 a0 = *(const float4*)&xs[(d << 5) + (tr << 2)];
                const float4 bq = *(const float4*)&cbase[j << 7];
                const float av[4] = {a0.x, a0.y, a0.z, a0.w};
                const float bv[4] = {bq.x, bq.y, bq.z, bq.w};
                #pragma unroll
                for (int i = 0; i < 4; ++i)
                    #pragma unroll
                    for (int jj = 0; jj < 4; ++jj)
                        acc[i][(kc << 2) + jj] = fmaf(av[i], bv[jj], acc[i][(kc << 2) + jj]);
            }
        }
    }

    // ---- epilogue: ref-exact fp32 dist; per-row argmin + softmax(-dist) ----
    float* enc = out + OFF_ENC;
    float invz[4];

    #pragma unroll
    for (int i = 0; i < 4; ++i) {
        const int row = (tr << 2) + i;
        const float xxr = sxx[row];
        float m = 1e30f; int bk = 0;
        #pragma unroll
        for (int c = 0; c < 16; ++c) {
            const int k = ((c >> 2) << 7) + (tc << 2) + (c & 3);   // ascending in c
            const float t1   = xxr + ce2[k];          // fp32 round @ ulp(~64)
            const float dist = t1 - 2.f * acc[i][c];  // fp32 round @ ulp(~64)
            acc[i][c] = dist;
            if (dist < m) { m = dist; bk = k; }       // strict <: lowest k kept
        }
        // lexicographic (min dist, min k) butterfly across the 32 lanes of row
        #pragma unroll
        for (int off = 1; off < 32; off <<= 1) {
            const float mo = __shfl_xor(m, off, 32);
            const int   ko = __shfl_xor(bk, off, 32);
            if (mo < m || (mo == m && ko < bk)) { m = mo; bk = ko; }
        }
        float z = 0.f;
        #pragma unroll
        for (int c = 0; c < 16; ++c) {
            const float e = __expf(m - acc[i][c]);    // softmax(-dist), shifted
            acc[i][c] = e; z += e;
        }
        #pragma unroll
        for (int off = 1; off < 32; off <<= 1) z += __shfl_xor(z, off, 32);
        invz[i] = 1.f / z;

        if (tc == 0) {
            sidx[row] = bk;
            enc[((size_t)b << 10) + row0 + row] = (float)bk;
        }
    }

    __syncthreads();   // all csT reads done; sidx visible

    // ---- softmax histogram: block-reduce in LDS (alias csT), partial to ws ----
    float* shist = csT;
    shist[t] = 0.f; shist[t + 256] = 0.f;
    __syncthreads();
    #pragma unroll
    for (int c = 0; c < 16; ++c) {
        const int k = ((c >> 2) << 7) + (tc << 2) + (c & 3);
        float cs = 0.f;
        #pragma unroll
        for (int i = 0; i < 4; ++i) cs += acc[i][c] * invz[i];
        atomicAdd(&shist[k], cs);
    }
    __syncthreads();
    {
        float* wsh = wso + WS_SHP + ((size_t)blk << 9);
        wsh[t]       = shist[t];
        wsh[t + 256] = shist[t + 256];
    }

    // ---- quantized output + loss partial (from sidx), vectorized ----
    const int r4 = (t & 7) << 2;           // row quad 0..28
    const int dq = t >> 3;                 // 0..31
    const int c0 = sidx[r4], c1 = sidx[r4 + 1], c2 = sidx[r4 + 2], c3 = sidx[r4 + 3];
    float lsum = 0.f;
    #pragma unroll
    for (int p = 0; p < 2; ++p) {
        const int d = (p << 5) + dq;
        float4 q;
        q.x = cb[(c0 << 6) + d];
        q.y = cb[(c1 << 6) + d];
        q.z = cb[(c2 << 6) + d];
        q.w = cb[(c3 << 6) + d];
        const float4 xv = *(const float4*)&xs[(d << 5) + r4];
        const float d0 = q.x - xv.x, d1 = q.y - xv.y, d2 = q.z - xv.z, d3 = q.w - xv.w;
        lsum = fmaf(d0, d0, lsum); lsum = fmaf(d1, d1, lsum);
        lsum = fmaf(d2, d2, lsum); lsum = fmaf(d3, d3, lsum);
        *(float4*)&out[(((size_t)(b << 6) + d) << 10) + row0 + r4] = q;
    }
    #pragma unroll
    for (int off = 1; off < 64; off <<= 1) lsum += __shfl_xor(lsum, off, 64);
    if ((t & 63) == 0) wso[WS_LOSS + (blk << 2) + (t >> 6)] = lsum;
}

// per-batch: sum 32 sh partials; rebuild ip histogram from enc indices
__global__ __launch_bounds__(512) void vq_reduce(const float* __restrict__ ws,
                                                 float* __restrict__ out)
{
    __shared__ int hist[512];
    const int b = blockIdx.x, t = threadIdx.x;
    const float* p = ws + WS_SHP + ((size_t)b << 14) + t;   // b*32*512
    float s = 0.f;
    #pragma unroll
    for (int j = 0; j < 32; ++j) s += p[j << 9];
    out[OFF_SH + (b << 9) + t] = s;
    hist[t] = 0;
    __syncthreads();
    const float* enc = out + OFF_ENC + ((size_t)b << 10);
    const int ca = (int)enc[t];
    const int cbn = (int)enc[t + 512];
    atomicAdd(&hist[ca], 1);
    atomicAdd(&hist[cbn], 1);
    __syncthreads();
    out[OFF_IP + (b << 9) + t] = (float)hist[t];
}

// loss sum + perplexity from per-batch code counts (512 threads, one k each)
__global__ __launch_bounds__(512) void vq_final(const float* __restrict__ ws,
                                                float* __restrict__ out)
{
    __shared__ float red[8], red2[8];
    const int t = threadIdx.x;
    const float* ip = out + OFF_IP;
    float c0 = 0.f, c1 = 0.f, c2 = 0.f, c3 = 0.f;
    #pragma unroll
    for (int bb = 0; bb < 64; bb += 4) {
        c0 += ip[((bb + 0) << 9) + t];
        c1 += ip[((bb + 1) << 9) + t];
        c2 += ip[((bb + 2) << 9) + t];
        c3 += ip[((bb + 3) << 9) + t];
    }
    const float c = (c0 + c1) + (c2 + c3);
    const float pav = c * (1.0f / 65536.f);
    float h = pav * logf(pav + 1e-10f);
    // loss partials: 8192 floats
    const float* wl = ws + WS_LOSS;
    float ls = 0.f;
    #pragma unroll
    for (int j = 0; j < 16; ++j) ls += wl[(j << 9) + t];
    #pragma unroll
    for (int off = 1; off < 64; off <<= 1) {
        h  += __shfl_xor(h, off, 64);
        ls += __shfl_xor(ls, off, 64);
    }
    if ((t & 63) == 0) { red[t >> 6] = h; red2[t >> 6] = ls; }
    __syncthreads();
    if (t == 0) {
        float H = 0.f, L = 0.f;
        #pragma unroll
        for (int w = 0; w < 8; ++w) { H += red[w]; L += red2[w]; }
        out[OFF_PERP] = expf(-H);
        out[OFF_LOSS] = L * (1.25f / 4194304.f);
    }
}

extern "C" void kernel_launch(void* const* d_in, const int* in_sizes, int n_in,
                              void* d_out, int out_size, void* d_ws, size_t ws_size,
                              hipStream_t stream)
{
    const float* x  = (const float*)d_in[0];
    const float* cb = (const float*)d_in[1];
    float* out = (float*)d_out;
    float* ws  = (float*)d_ws;
    (void)ws_size;   // requires >= 4.4 MB (1090048 floats)

    vq_prep  <<<32,   256, 0, stream>>>(cb, ws);
    vq_main  <<<2048, 256, 0, stream>>>(x, cb, ws, ws, out);
    vq_reduce<<<64,   512, 0, stream>>>(ws, out);
    vq_final <<<1,    512, 0, stream>>>(ws, out);
}

// Round 5
// 190.493 us; speedup vs baseline: 1.1903x; 1.1903x over previous
//
#include <hip/hip_runtime.h>

// Problem constants (fixed by setup_inputs):
//   x: [B=64, D=64, H=32, W=32] fp32   -> N = B*H*W = 65536 rows of D=64
//   codebook: [K=512, D=64] fp32
// Output layout (all fp32, concatenated flat in return order):
//   [0 .. 4194304)        quant_out [B,D,H,W]
//   [4194304]             loss
//   [4194305]             perplexity
//   [4194306 .. +65536)   encoding_indice [B, H*W] (as float)
//   [4259842 .. +32768)   index_program [B,K]
//   [4292610 .. +32768)   softmax_histogram [B,K]

#define OFF_LOSS 4194304
#define OFF_PERP 4194305
#define OFF_ENC  4194306
#define OFF_IP   4259842
#define OFF_SH   4292610

// Workspace layout (floats). Requires ws_size >= 1090048*4 B = 4.4 MB.
#define WS_CBT   0
#define WS_CE2   32768
#define WS_SHP   33280
#define WS_LOSS  1081856

// R12 change (storage class only; math bit-identical per (row,k)):
//  - R11 post-mortem: (256,1) changed NOTHING (VGPR 80, WRITE 220 MB, same
//    dur). Excess write = 380 B/thread = 96 floats = acc[4][16] + pv[8]
//    exactly: the arrays were ALLOCAS IN SCRATCH all along (rule-#20 trap);
//    launch bounds were never the lever, SROA simply never promoted them.
//  - Fix: no local arrays. acc -> four ext_vector(16) SSA values with
//    literal-only element indices (kc/epilogue hand-unrolled via macros);
//    pv[8] -> eight named float4; invz -> four scalars. Constant-index
//    vector subscripts are insertelement/extractelement in SSA: clang emits
//    no alloca, so there is nothing left to live in scratch.

typedef float f16v __attribute__((ext_vector_type(16)));

__global__ __launch_bounds__(256) void vq_prep(const float* __restrict__ cb,
                                               float* __restrict__ ws)
{
    const int t  = blockIdx.x * 256 + threadIdx.x;   // 0..8191
    const int kg = t >> 4;                           // code 0..511
    const int j  = t & 15;                           // float4 index along D
    const float4 v = ((const float4*)cb)[(kg << 4) + j];
    float pr = v.x * v.x + v.y * v.y + v.z * v.z + v.w * v.w;
    #pragma unroll
    for (int off = 1; off < 16; off <<= 1) pr += __shfl_xor(pr, off, 16);
    if (j == 0) ws[WS_CE2 + kg] = pr;
    // transposed, chunk-major: ws[WS_CBT + kc*8192 + d*128 + kl]
    const int kc = kg >> 7, kl = kg & 127;
    float* base = ws + WS_CBT + (kc << 13) + (j << 9) + kl;   // d = 4*j
    base[0]   = v.x;
    base[128] = v.y;
    base[256] = v.z;
    base[384] = v.w;
}

// ---- macro kit: all acc element indices are integer literals ----
#define FMA4(ACC, AV, K4) \
    ACC[(K4) + 0] = fmaf((AV), bq.x, ACC[(K4) + 0]); \
    ACC[(K4) + 1] = fmaf((AV), bq.y, ACC[(K4) + 1]); \
    ACC[(K4) + 2] = fmaf((AV), bq.z, ACC[(K4) + 2]); \
    ACC[(K4) + 3] = fmaf((AV), bq.w, ACC[(K4) + 3]);

#define ST_CST() do { \
    float4* c4 = (float4*)csT; \
    c4[t] = pv0; c4[256 + t] = pv1; c4[512 + t] = pv2; c4[768 + t] = pv3; \
    c4[1024 + t] = pv4; c4[1280 + t] = pv5; c4[1536 + t] = pv6; c4[1792 + t] = pv7; \
} while (0)

#define PREFETCH(KC1) do { \
    pv0 = cbT4[((KC1) << 11) + t];        pv1 = cbT4[((KC1) << 11) + 256 + t]; \
    pv2 = cbT4[((KC1) << 11) + 512 + t];  pv3 = cbT4[((KC1) << 11) + 768 + t]; \
    pv4 = cbT4[((KC1) << 11) + 1024 + t]; pv5 = cbT4[((KC1) << 11) + 1280 + t]; \
    pv6 = cbT4[((KC1) << 11) + 1536 + t]; pv7 = cbT4[((KC1) << 11) + 1792 + t]; \
} while (0)

// One 128-code chunk: stage csT, prefetch next, 64-d FMA sweep.
// Same op order as R10/R11: kc outer (literal), db, j ascending; i then jj.
#define GEMM_CHUNK(KC) do { \
    __syncthreads(); \
    ST_CST(); \
    if ((KC) < 3) PREFETCH((KC) + 1); \
    __syncthreads(); \
    _Pragma("unroll 2") \
    for (int db = 0; db < 16; ++db) { \
        const float* cbase = &csT[(db << 9) + (tc << 2)]; \
        _Pragma("unroll") \
        for (int j = 0; j < 4; ++j) { \
            const int d = (db << 2) + j; \
            const float4 a0 = *(const float4*)&xs[(d << 5) + (tr << 2)]; \
            const float4 bq = *(const float4*)&cbase[j << 7]; \
            FMA4(acc0, a0.x, (KC) << 2) \
            FMA4(acc1, a0.y, (KC) << 2) \
            FMA4(acc2, a0.z, (KC) << 2) \
            FMA4(acc3, a0.w, (KC) << 2) \
        } \
    } \
} while (0)

#define EPI_C(C, ACC) { \
    const int k = (((C) >> 2) << 7) + (tc << 2) + ((C) & 3); \
    const float t1 = xxr + ce2[k]; \
    const float dist = t1 - 2.f * ACC[C]; \
    ACC[C] = dist; \
    if (dist < m) { m = dist; bk = k; } }

#define EXP_C(C, ACC) { \
    const float e = __expf(m - ACC[C]); \
    ACC[C] = e; z += e; }

#define ROW_EPI(I, ACC, INVZ) do { \
    const int row = (tr << 2) + (I); \
    const float xxr = sxx[row]; \
    float m = 1e30f; int bk = 0; \
    EPI_C(0, ACC)  EPI_C(1, ACC)  EPI_C(2, ACC)  EPI_C(3, ACC) \
    EPI_C(4, ACC)  EPI_C(5, ACC)  EPI_C(6, ACC)  EPI_C(7, ACC) \
    EPI_C(8, ACC)  EPI_C(9, ACC)  EPI_C(10, ACC) EPI_C(11, ACC) \
    EPI_C(12, ACC) EPI_C(13, ACC) EPI_C(14, ACC) EPI_C(15, ACC) \
    _Pragma("unroll") \
    for (int off = 1; off < 32; off <<= 1) { \
        const float mo = __shfl_xor(m, off, 32); \
        const int   ko = __shfl_xor(bk, off, 32); \
        if (mo < m || (mo == m && ko < bk)) { m = mo; bk = ko; } \
    } \
    float z = 0.f; \
    EXP_C(0, ACC)  EXP_C(1, ACC)  EXP_C(2, ACC)  EXP_C(3, ACC) \
    EXP_C(4, ACC)  EXP_C(5, ACC)  EXP_C(6, ACC)  EXP_C(7, ACC) \
    EXP_C(8, ACC)  EXP_C(9, ACC)  EXP_C(10, ACC) EXP_C(11, ACC) \
    EXP_C(12, ACC) EXP_C(13, ACC) EXP_C(14, ACC) EXP_C(15, ACC) \
    _Pragma("unroll") \
    for (int off = 1; off < 32; off <<= 1) z += __shfl_xor(z, off, 32); \
    INVZ = 1.f / z; \
    if (tc == 0) { \
        sidx[row] = bk; \
        enc[((size_t)b << 10) + row0 + row] = (float)bk; \
    } \
} while (0)

#define HIST_C(C) { \
    const int k = (((C) >> 2) << 7) + (tc << 2) + ((C) & 3); \
    float cs = 0.f; \
    cs += acc0[C] * invz0; cs += acc1[C] * invz1; \
    cs += acc2[C] * invz2; cs += acc3[C] * invz3; \
    atomicAdd(&shist[k], cs); }

__global__ __launch_bounds__(256, 1) void vq_main(
    const float* __restrict__ x, const float* __restrict__ cb,
    const float* __restrict__ wsc,   // cbT + ce2 (read-only region)
    float* __restrict__ wso,         // sh + loss partials (write-only region)
    float* __restrict__ out)
{
    __shared__ float  xs[64 * 32];     // xs[d*32 + r], transposed x tile (32 rows)
    __shared__ float  csT[64 * 128];   // [d][k] for current 128-code chunk
    __shared__ float  ce2[512];        // ||e_k||^2 (fp32)
    __shared__ float  sxx[32];         // ||x_r||^2 (fp32) per row
    __shared__ int    sidx[32];        // argmin code per row

    const int t    = threadIdx.x;
    const int blk  = blockIdx.x;        // 0..2047
    const int b    = blk >> 5;          // batch index
    const int row0 = (blk & 31) << 5;   // row offset within batch (H*W space)
    const int tr   = t >> 5;            // 0..7  (row group: rows tr*4..tr*4+3)
    const int tc   = t & 31;            // 0..31 (col group)

    const float4* cbT4 = (const float4*)(wsc + WS_CBT);

    // ---- stage x tile as float4 (512 float4, 2 per thread, coalesced) ----
    {
        const float4* xb4 = (const float4*)(x + ((size_t)b << 16) + row0);
        #pragma unroll
        for (int p = 0; p < 2; ++p) {
            const int fi = (p << 8) + t;      // 0..511
            const int d  = fi >> 3;
            const int r4 = fi & 7;
            *(float4*)&xs[(d << 5) + (r4 << 2)] = xb4[(d << 8) + r4];
        }
    }
    // ---- stage ce2 from ws ----
    if (t < 128) ((float4*)ce2)[t] = ((const float4*)(wsc + WS_CE2))[t];

    // ---- prefetch chunk 0 of transposed codebook into registers ----
    float4 pv0, pv1, pv2, pv3, pv4, pv5, pv6, pv7;
    PREFETCH(0);

    __syncthreads();
    // ---- ||x_r||^2 fp32, sequential fmaf over d (bit-exact) ----
    if (t < 32) {
        float s = 0.f;
        for (int d = 0; d < 64; ++d) { const float v = xs[(d << 5) + t]; s = fmaf(v, v, s); }
        sxx[t] = s;
    }

    f16v acc0 = 0.f, acc1 = 0.f, acc2 = 0.f, acc3 = 0.f;

    // ---- GEMM: 4 chunks of 128 codes (kc literal -> all acc indices literal) ----
    GEMM_CHUNK(0);
    GEMM_CHUNK(1);
    GEMM_CHUNK(2);
    GEMM_CHUNK(3);

    // ---- epilogue: ref-exact fp32 dist; per-row argmin + softmax(-dist) ----
    float* enc = out + OFF_ENC;
    float invz0, invz1, invz2, invz3;
    ROW_EPI(0, acc0, invz0);
    ROW_EPI(1, acc1, invz1);
    ROW_EPI(2, acc2, invz2);
    ROW_EPI(3, acc3, invz3);

    __syncthreads();   // all csT reads done; sidx visible

    // ---- softmax histogram: block-reduce in LDS (alias csT), partial to ws ----
    float* shist = csT;
    shist[t] = 0.f; shist[t + 256] = 0.f;
    __syncthreads();
    HIST_C(0)  HIST_C(1)  HIST_C(2)  HIST_C(3)
    HIST_C(4)  HIST_C(5)  HIST_C(6)  HIST_C(7)
    HIST_C(8)  HIST_C(9)  HIST_C(10) HIST_C(11)
    HIST_C(12) HIST_C(13) HIST_C(14) HIST_C(15)
    __syncthreads();
    {
        float* wsh = wso + WS_SHP + ((size_t)blk << 9);
        wsh[t]       = shist[t];
        wsh[t + 256] = shist[t + 256];
    }

    // ---- quantized output + loss partial (from sidx), vectorized ----
    const int r4 = (t & 7) << 2;           // row quad 0..28
    const int dq = t >> 3;                 // 0..31
    const int c0 = sidx[r4], c1 = sidx[r4 + 1], c2 = sidx[r4 + 2], c3 = sidx[r4 + 3];
    float lsum = 0.f;
    #pragma unroll
    for (int p = 0; p < 2; ++p) {
        const int d = (p << 5) + dq;
        float4 q;
        q.x = cb[(c0 << 6) + d];
        q.y = cb[(c1 << 6) + d];
        q.z = cb[(c2 << 6) + d];
        q.w = cb[(c3 << 6) + d];
        const float4 xv = *(const float4*)&xs[(d << 5) + r4];
        const float d0 = q.x - xv.x, d1 = q.y - xv.y, d2 = q.z - xv.z, d3 = q.w - xv.w;
        lsum = fmaf(d0, d0, lsum); lsum = fmaf(d1, d1, lsum);
        lsum = fmaf(d2, d2, lsum); lsum = fmaf(d3, d3, lsum);
        *(float4*)&out[(((size_t)(b << 6) + d) << 10) + row0 + r4] = q;
    }
    #pragma unroll
    for (int off = 1; off < 64; off <<= 1) lsum += __shfl_xor(lsum, off, 64);
    if ((t & 63) == 0) wso[WS_LOSS + (blk << 2) + (t >> 6)] = lsum;
}

// per-batch: sum 32 sh partials; rebuild ip histogram from enc indices
__global__ __launch_bounds__(512) void vq_reduce(const float* __restrict__ ws,
                                                 float* __restrict__ out)
{
    __shared__ int hist[512];
    const int b = blockIdx.x, t = threadIdx.x;
    const float* p = ws + WS_SHP + ((size_t)b << 14) + t;   // b*32*512
    float s = 0.f;
    #pragma unroll
    for (int j = 0; j < 32; ++j) s += p[j << 9];
    out[OFF_SH + (b << 9) + t] = s;
    hist[t] = 0;
    __syncthreads();
    const float* enc = out + OFF_ENC + ((size_t)b << 10);
    const int ca = (int)enc[t];
    const int cbn = (int)enc[t + 512];
    atomicAdd(&hist[ca], 1);
    atomicAdd(&hist[cbn], 1);
    __syncthreads();
    out[OFF_IP + (b << 9) + t] = (float)hist[t];
}

// loss sum + perplexity from per-batch code counts (512 threads, one k each)
__global__ __launch_bounds__(512) void vq_final(const float* __restrict__ ws,
                                                float* __restrict__ out)
{
    __shared__ float red[8], red2[8];
    const int t = threadIdx.x;
    const float* ip = out + OFF_IP;
    float c0 = 0.f, c1 = 0.f, c2 = 0.f, c3 = 0.f;
    #pragma unroll
    for (int bb = 0; bb < 64; bb += 4) {
        c0 += ip[((bb + 0) << 9) + t];
        c1 += ip[((bb + 1) << 9) + t];
        c2 += ip[((bb + 2) << 9) + t];
        c3 += ip[((bb + 3) << 9) + t];
    }
    const float c = (c0 + c1) + (c2 + c3);
    const float pav = c * (1.0f / 65536.f);
    float h = pav * logf(pav + 1e-10f);
    // loss partials: 8192 floats
    const float* wl = ws + WS_LOSS;
    float ls = 0.f;
    #pragma unroll
    for (int j = 0; j < 16; ++j) ls += wl[(j << 9) + t];
    #pragma unroll
    for (int off = 1; off < 64; off <<= 1) {
        h  += __shfl_xor(h, off, 64);
        ls += __shfl_xor(ls, off, 64);
    }
    if ((t & 63) == 0) { red[t >> 6] = h; red2[t >> 6] = ls; }
    __syncthreads();
    if (t == 0) {
        float H = 0.f, L = 0.f;
        #pragma unroll
        for (int w = 0; w < 8; ++w) { H += red[w]; L += red2[w]; }
        out[OFF_PERP] = expf(-H);
        out[OFF_LOSS] = L * (1.25f / 4194304.f);
    }
}

extern "C" void kernel_launch(void* const* d_in, const int* in_sizes, int n_in,
                              void* d_out, int out_size, void* d_ws, size_t ws_size,
                              hipStream_t stream)
{
    const float* x  = (const float*)d_in[0];
    const float* cb = (const float*)d_in[1];
    float* out = (float*)d_out;
    float* ws  = (float*)d_ws;
    (void)ws_size;   // requires >= 4.4 MB (1090048 floats)

    vq_prep  <<<32,   256, 0, stream>>>(cb, ws);
    vq_main  <<<2048, 256, 0, stream>>>(x, cb, ws, ws, out);
    vq_reduce<<<64,   512, 0, stream>>>(ws, out);
    vq_final <<<1,    512, 0, stream>>>(ws, out);
}